// Round 3
// baseline (215.285 us; speedup 1.0000x reference)
//
#include <hip/hip_runtime.h>
#include <cstdint>
#include <cstddef>

#define NNODES 50000
#define NEDGES 800000
#define MEDGES (NEDGES + NNODES)
#define FIN    256
#define HID    96
#define NCLS   32
#define NEG_SLOPE 0.2f

#define NBUCK  391      // ceil(50000/128): 128-node dst ranges
#define BCAP   3072     // per-bucket staging capacity (mean 2176, sigma ~45)

typedef unsigned int uint32;
typedef __attribute__((ext_vector_type(8))) short short8;   // 8 bf16 = 4 VGPR
typedef __attribute__((ext_vector_type(4))) float f32x4;    // MFMA acc

__device__ __forceinline__ ushort bf_round(float f) {
    uint32 u = __float_as_uint(f);
    u += 0x7FFFu + ((u >> 16) & 1u);            // RNE
    return (ushort)(u >> 16);
}
__device__ __forceinline__ uint32 pack_bf16x2(float a, float b) {
    return (uint32)bf_round(a) | ((uint32)bf_round(b) << 16);
}
__device__ __forceinline__ float bf_lo(uint32 u) { return __uint_as_float(u << 16); }
__device__ __forceinline__ float bf_hi(uint32 u) { return __uint_as_float(u & 0xFFFF0000u); }
__device__ __forceinline__ float lrelu(float t) { return (t > 0.f) ? t : NEG_SLOPE * t; }
__device__ __forceinline__ float af(int i) { return __int_as_float(i); }
__device__ __forceinline__ float elu_fast(float t) { return (t > 0.f) ? t : (__expf(t) - 1.f); }

// ---------------- W1-pack + gcount zero (must precede bucket1's atomics) ----------------

__global__ __launch_bounds__(256) void packw_kernel(const float* __restrict__ W1,
                                                    ushort* __restrict__ W1p,
                                                    int* __restrict__ gcount) {
    int stride = gridDim.x * 256;
    for (int idx = blockIdx.x * 256 + threadIdx.x; idx < NBUCK; idx += stride)
        gcount[idx] = 0;
    for (int idx = blockIdx.x * 256 + threadIdx.x; idx < 6 * 8 * 64 * 8; idx += stride) {
        int j     = idx & 7;
        int lane  = (idx >> 3) & 63;
        int kstep = (idx >> 9) & 7;
        int ntile = idx >> 12;
        int k = kstep * 32 + ((lane >> 4) << 3) + j;
        int n = ntile * 16 + (lane & 15);
        W1p[idx] = bf_round(W1[(size_t)k * 96 + n]);
    }
}

// ---------------- CSR build pass 1: bucketed staging ----------------
// staging entry packed: src (16 bits, 50000<65536) | (dst&127)<<16.

__global__ __launch_bounds__(256) void bucket1_kernel(const int* __restrict__ ei,
                                                      int* __restrict__ gcount,
                                                      int* __restrict__ staging) {
    __shared__ int hist[NBUCK];
    __shared__ int base_sh[NBUCK];
    for (int i = threadIdx.x; i < NBUCK; i += 256) hist[i] = 0;
    __syncthreads();

    int v[8], rk[8], bk[8];
    int e0 = blockIdx.x * 2048;
#pragma unroll
    for (int i = 0; i < 8; ++i) {
        int e = e0 + i * 256 + threadIdx.x;
        if (e < MEDGES) {
            int s, d;
            if (e < NEDGES) { s = ei[e]; d = ei[NEDGES + e]; }
            else            { s = e - NEDGES; d = s; }
            bk[i] = d >> 7;
            v[i]  = s | ((d & 127) << 16);
            rk[i] = atomicAdd(&hist[bk[i]], 1);
        } else bk[i] = -1;
    }
    __syncthreads();
    for (int i = threadIdx.x; i < NBUCK; i += 256) {
        int c = hist[i];
        base_sh[i] = c ? atomicAdd(&gcount[i], c) : 0;
    }
    __syncthreads();
#pragma unroll
    for (int i = 0; i < 8; ++i) {
        if (bk[i] >= 0) {
            int pos = base_sh[bk[i]] + rk[i];
            if (pos < BCAP)
                staging[(size_t)bk[i] * BCAP + pos] = v[i];
        }
    }
}

// ---------------- merged dispatch: bucket2 (blocks 0..390) + gemm1 (391..1172) ----------------

__global__ __launch_bounds__(256) void b2gemm1_kernel(const int* __restrict__ staging,
                                                      const int* __restrict__ gcount,
                                                      int* __restrict__ rowptr,
                                                      int* __restrict__ esrc,
                                                      const float* __restrict__ x,
                                                      const ushort* __restrict__ W1p,
                                                      const float* __restrict__ a_src,
                                                      const float* __restrict__ a_dst,
                                                      ushort* __restrict__ h1,
                                                      float* __restrict__ as1,
                                                      float* __restrict__ ad1) {
    __shared__ int dcount[128];
    __shared__ int dincl[128];
    __shared__ int dexcl[128];
    __shared__ int fillc[128];
    __shared__ int red_s[256];

    if (blockIdx.x < NBUCK) {
        // ---- bucket2: rowptr + esrc build for bucket b ----
        const int b = blockIdx.x;
        const int t = threadIdx.x;

        int pv = 0;
        for (int idx = t; idx < b; idx += 256) pv += gcount[idx];
        red_s[t] = pv;
        __syncthreads();
        for (int off2 = 128; off2; off2 >>= 1) {
            if (t < off2) red_s[t] += red_s[t + off2];
            __syncthreads();
        }
        const int ebase = red_s[0];
        const int cnt   = gcount[b];
        const int node0 = b << 7;
        const int* st   = staging + (size_t)b * BCAP;

        for (int i = t; i < 128; i += 256) { dcount[i] = 0; fillc[i] = 0; }
        __syncthreads();

        for (int i = t; i < cnt; i += 256)
            atomicAdd(&dcount[st[i] >> 16], 1);
        __syncthreads();

        if (t < 128) dincl[t] = dcount[t];
        __syncthreads();
        for (int off = 1; off < 128; off <<= 1) {
            int val = (t >= off && t < 128) ? dincl[t - off] : 0;
            __syncthreads();
            if (t < 128) dincl[t] += val;
            __syncthreads();
        }
        if (t < 128) {
            int excl = dincl[t] - dcount[t];
            dexcl[t] = excl;
            int node = node0 + t;
            if (node < NNODES) rowptr[node] = ebase + excl;
        }
        if (b == NBUCK - 1 && t == 0) rowptr[NNODES] = MEDGES;
        __syncthreads();

        for (int i = t; i < cnt; i += 256) {
            int v = st[i];
            int dd = v >> 16;
            int r = atomicAdd(&fillc[dd], 1);
            esrc[ebase + dexcl[dd] + r] = v & 0xFFFF;
        }
        return;
    }

    // ---- gemm1: h1(bf16) = x @ W1 (+ fused alpha dots) ----
    const int tid  = threadIdx.x;
    const int lane = tid & 63;
    const int wv   = tid >> 6;
    const int m    = lane & 15;
    const int quad = lane >> 4;
    const int node0 = (blockIdx.x - NBUCK) * 64;

    int arow = node0 + wv * 16 + m;
    if (arow >= NNODES) arow = NNODES - 1;
    const float* xr = x + (size_t)arow * FIN + quad * 8;

    const short8* Wp = (const short8*)W1p;

    f32x4 acc[6];
#pragma unroll
    for (int t = 0; t < 6; ++t) acc[t] = (f32x4){0.f, 0.f, 0.f, 0.f};

#pragma unroll
    for (int ks = 0; ks < 8; ++ks) {
        float4 v0 = *(const float4*)(xr + ks * 32);
        float4 v1 = *(const float4*)(xr + ks * 32 + 4);
        short8 a;
        a[0] = (short)bf_round(v0.x); a[1] = (short)bf_round(v0.y);
        a[2] = (short)bf_round(v0.z); a[3] = (short)bf_round(v0.w);
        a[4] = (short)bf_round(v1.x); a[5] = (short)bf_round(v1.y);
        a[6] = (short)bf_round(v1.z); a[7] = (short)bf_round(v1.w);
#pragma unroll
        for (int t = 0; t < 6; ++t) {
            short8 b = Wp[(t * 8 + ks) * 64 + lane];
            acc[t] = __builtin_amdgcn_mfma_f32_16x16x32_bf16(a, b, acc[t], 0, 0, 0);
        }
    }

    float as_reg[6], ad_reg[6];
#pragma unroll
    for (int t = 0; t < 6; ++t) {
        as_reg[t] = a_src[t * 16 + m];
        ad_reg[t] = a_dst[t * 16 + m];
    }

#pragma unroll
    for (int r = 0; r < 4; ++r) {
        int node = node0 + wv * 16 + quad * 4 + r;
        float ps = 0.f, pd = 0.f;
#pragma unroll
        for (int t = 0; t < 6; ++t) {
            ps += acc[t][r] * as_reg[t];
            pd += acc[t][r] * ad_reg[t];
        }
#pragma unroll
        for (int off = 1; off < 16; off <<= 1) {
            ps += __shfl_xor(ps, off);
            pd += __shfl_xor(pd, off);
        }
        if (node < NNODES) {
            ushort* hp = h1 + (size_t)node * 96 + m;
#pragma unroll
            for (int t = 0; t < 6; ++t) hp[t * 16] = bf_round(acc[t][r]);
            if (m == 0) { as1[node] = ps; ad1[node] = pd; }
        }
    }
}

// ---------------- Fused attn+agg layer 1 + gemm2 epilogue (latency-pipelined) ----------------
// Half-wave (32 lanes) per node. Gather addresses depend only on src indices,
// NOT on softmax alphas -> write ss[] immediately, issue the first 16 row
// gathers, and hide the whole softmax + W2 staging + barrier under them.
// Block loop is depth-2 software-pipelined (uA/uB named reg buffers, literal
// indices only). W2 staged UNTRANSPOSED (W2n[k][c]): lane c reads bank c ->
// conflict-free broadcast reads (kills the 1.8M bank conflicts).

#define LOADB(U, qa, qb) do { \
    U[0] = ((const uint2*)(h + (size_t)(qa).x * 96))[fl]; \
    U[1] = ((const uint2*)(h + (size_t)(qa).y * 96))[fl]; \
    U[2] = ((const uint2*)(h + (size_t)(qa).z * 96))[fl]; \
    U[3] = ((const uint2*)(h + (size_t)(qa).w * 96))[fl]; \
    U[4] = ((const uint2*)(h + (size_t)(qb).x * 96))[fl]; \
    U[5] = ((const uint2*)(h + (size_t)(qb).y * 96))[fl]; \
    U[6] = ((const uint2*)(h + (size_t)(qb).z * 96))[fl]; \
    U[7] = ((const uint2*)(h + (size_t)(qb).w * 96))[fl]; \
} while (0)

#define CONSUME(U, aL, aH) do { \
    acc0 += (aL).x*bf_lo(U[0].x) + (aL).y*bf_lo(U[1].x) + (aL).z*bf_lo(U[2].x) + (aL).w*bf_lo(U[3].x) \
          + (aH).x*bf_lo(U[4].x) + (aH).y*bf_lo(U[5].x) + (aH).z*bf_lo(U[6].x) + (aH).w*bf_lo(U[7].x); \
    acc1 += (aL).x*bf_hi(U[0].x) + (aL).y*bf_hi(U[1].x) + (aL).z*bf_hi(U[2].x) + (aL).w*bf_hi(U[3].x) \
          + (aH).x*bf_hi(U[4].x) + (aH).y*bf_hi(U[5].x) + (aH).z*bf_hi(U[6].x) + (aH).w*bf_hi(U[7].x); \
    acc2 += (aL).x*bf_lo(U[0].y) + (aL).y*bf_lo(U[1].y) + (aL).z*bf_lo(U[2].y) + (aL).w*bf_lo(U[3].y) \
          + (aH).x*bf_lo(U[4].y) + (aH).y*bf_lo(U[5].y) + (aH).z*bf_lo(U[6].y) + (aH).w*bf_lo(U[7].y); \
    acc3 += (aL).x*bf_hi(U[0].y) + (aL).y*bf_hi(U[1].y) + (aL).z*bf_hi(U[2].y) + (aL).w*bf_hi(U[3].y) \
          + (aH).x*bf_hi(U[4].y) + (aH).y*bf_hi(U[5].y) + (aH).z*bf_hi(U[6].y) + (aH).w*bf_hi(U[7].y); \
} while (0)

__global__ __launch_bounds__(256) void agg96g2_kernel(const ushort* __restrict__ h,
                                                      const float* __restrict__ asrc,
                                                      const float* __restrict__ adst,
                                                      const float* __restrict__ bias,
                                                      const int* __restrict__ rowptr,
                                                      const int* __restrict__ esrc,
                                                      const float* __restrict__ W2,
                                                      const float* __restrict__ a2s,
                                                      const float* __restrict__ a2d,
                                                      uint32* __restrict__ h2b,
                                                      float* __restrict__ as2,
                                                      float* __restrict__ ad2) {
    __shared__ __align__(16) int   ss[4][2][32];
    __shared__ __align__(16) float aa[4][2][32];
    __shared__ __align__(16) float W2n[96 * 32];      // [k][c] untransposed
    __shared__ __align__(16) float y_sh[4][2][96];

    const int wave = threadIdx.x >> 6;
    const int lane = threadIdx.x & 63;
    const int hf   = lane >> 5;
    const int fl32 = lane & 31;
    const int i = blockIdx.x * 8 + wave * 2 + hf;   // 50000 = 8*6250 exact

    const int start = rowptr[i];
    const int deg   = rowptr[i + 1] - start;
    const float ad  = adst[i];
    const float a2s_v = a2s[fl32];
    const float a2d_v = a2d[fl32];
    const int fl    = (fl32 < 24) ? fl32 : 23;

    float acc0 = 0.f, acc1 = 0.f, acc2 = 0.f, acc3 = 0.f;

    const bool small = (deg <= 32);
    int s_reg = 0, nb = 0;
    uint2 uA[8], uB[8];

    if (small) {
        // src indices + first 16 gathers in flight BEFORE softmax/staging
        bool valid = fl32 < deg;
        s_reg = valid ? esrc[start + fl32] : 0;
        ss[wave][hf][fl32] = s_reg;
        nb = (deg + 7) >> 3;                       // 1..4 blocks of 8 edges
        const int4* ssp = (const int4*)&ss[wave][hf][0];
        {
            int4 qa = ssp[0], qb = ssp[1];
            LOADB(uA, qa, qb);
        }
        if (nb > 1) {
            int4 qa = ssp[2], qb = ssp[3];
            LOADB(uB, qa, qb);
        }
    }

    // stage W2 while gathers are in flight
    for (int idx = threadIdx.x; idx < 96 * 32; idx += 256)
        W2n[idx] = W2[idx];
    __syncthreads();

    if (small) {
        bool valid = fl32 < deg;
        float e = valid ? lrelu(asrc[s_reg] + ad) : -1e30f;
        float mx = e;
#pragma unroll
        for (int off = 16; off; off >>= 1) mx = fmaxf(mx, __shfl_xor(mx, off));
        float ex = valid ? __expf(e - mx) : 0.f;
        float sum = ex;
#pragma unroll
        for (int off = 16; off; off >>= 1) sum += __shfl_xor(sum, off);
        aa[wave][hf][fl32] = ex / sum;             // 0 for padded lanes
        const float4* aap = (const float4*)&aa[wave][hf][0];
        const int4*  ssp = (const int4*)&ss[wave][hf][0];

        { float4 aL = aap[0], aH = aap[1]; CONSUME(uA, aL, aH); }
        if (nb > 2) { int4 qa = ssp[4], qb = ssp[5]; LOADB(uA, qa, qb); }
        if (nb > 1) { float4 aL = aap[2], aH = aap[3]; CONSUME(uB, aL, aH); }
        if (nb > 3) { int4 qa = ssp[6], qb = ssp[7]; LOADB(uB, qa, qb); }
        if (nb > 2) { float4 aL = aap[4], aH = aap[5]; CONSUME(uA, aL, aH); }
        if (nb > 3) { float4 aL = aap[6], aH = aap[7]; CONSUME(uB, aL, aH); }
    } else {
        float mx = -1e30f;
        for (int p = start + fl32; p < start + deg; p += 32)
            mx = fmaxf(mx, lrelu(asrc[esrc[p]] + ad));
#pragma unroll
        for (int off = 16; off; off >>= 1) mx = fmaxf(mx, __shfl_xor(mx, off));
        float sum = 0.f;
        for (int p = start + fl32; p < start + deg; p += 32)
            sum += __expf(lrelu(asrc[esrc[p]] + ad) - mx);
#pragma unroll
        for (int off = 16; off; off >>= 1) sum += __shfl_xor(sum, off);
        float inv = 1.f / sum;
        for (int e = 0; e < deg; ++e) {
            int s = esrc[start + e];
            float a = __expf(lrelu(asrc[s] + ad) - mx) * inv;
            uint2 u = ((const uint2*)(h + (size_t)s * 96))[fl];
            acc0 += a * bf_lo(u.x);
            acc1 += a * bf_hi(u.x);
            acc2 += a * bf_lo(u.y);
            acc3 += a * bf_hi(u.y);
        }
    }

    // ---- epilogue: bias + ELU -> y_sh, then fused h2 = y @ W2 ----
    if (fl32 < 24) {
        float* yp = &y_sh[wave][hf][4 * fl32];
        yp[0] = elu_fast(acc0 + bias[4 * fl32 + 0]);
        yp[1] = elu_fast(acc1 + bias[4 * fl32 + 1]);
        yp[2] = elu_fast(acc2 + bias[4 * fl32 + 2]);
        yp[3] = elu_fast(acc3 + bias[4 * fl32 + 3]);
    }
    asm volatile("s_waitcnt lgkmcnt(0)" ::: "memory");   // wave-internal y_sh visibility

    const float* yrow = &y_sh[wave][hf][0];
    float h2c = 0.f;
#pragma unroll
    for (int k4 = 0; k4 < 96; k4 += 4) {
        float4 yv = *(const float4*)(yrow + k4);       // broadcast within half
        h2c = fmaf(yv.x, W2n[(k4 + 0) * 32 + fl32], h2c);   // lane c -> bank c
        h2c = fmaf(yv.y, W2n[(k4 + 1) * 32 + fl32], h2c);
        h2c = fmaf(yv.z, W2n[(k4 + 2) * 32 + fl32], h2c);
        h2c = fmaf(yv.w, W2n[(k4 + 3) * 32 + fl32], h2c);
    }

    float ps = h2c * a2s_v;
    float pd = h2c * a2d_v;
#pragma unroll
    for (int off = 1; off < 32; off <<= 1) {        // reduce within 32-lane half
        ps += __shfl_xor(ps, off);
        pd += __shfl_xor(pd, off);
    }
    float partner = __shfl_xor(h2c, 16);            // class c+16 for c<16
    if (fl32 < 16)
        h2b[(size_t)i * 16 + fl32] = pack_bf16x2(h2c, partner);
    if (fl32 == 0) { as2[i] = ps; ad2[i] = pd; }
}

// ---------------- Fused attn + aggregation layer 2: TWO nodes per wave ----------------
// Half-wave per node; 4 groups x 8 lanes read 64 B h2b rows via dwordx2
// -> 8 edges per wave-VMEM-instruction across 2 independent streams.
// h2b uint32 index m holds feats (m, m+16).

__global__ __launch_bounds__(256) void agg32_kernel(const uint32* __restrict__ h2b,
                                                    const float* __restrict__ asrc,
                                                    const float* __restrict__ adst,
                                                    const float* __restrict__ bias,
                                                    const int* __restrict__ rowptr,
                                                    const int* __restrict__ esrc,
                                                    float* __restrict__ out) {
    __shared__ int2 sa[4][2][32];
    const int wave = threadIdx.x >> 6;
    const int lane = threadIdx.x & 63;
    const int hf   = lane >> 5;
    const int fl32 = lane & 31;
    const int i = blockIdx.x * 8 + wave * 2 + hf;   // 6250 blocks exact

    const int start = rowptr[i];
    const int deg   = rowptr[i + 1] - start;
    const float ad  = adst[i];
    const int g  = fl32 >> 3;        // edge group 0..3 within half
    const int fl = fl32 & 7;         // uint2 index within row

    float acc[4];
#pragma unroll
    for (int j = 0; j < 4; ++j) acc[j] = 0.f;

    if (deg <= 32) {
        bool valid = fl32 < deg;
        int s_reg = valid ? esrc[start + fl32] : 0;
        float e = valid ? lrelu(asrc[s_reg] + ad) : -1e30f;
        float mx = e;
#pragma unroll
        for (int off = 16; off; off >>= 1) mx = fmaxf(mx, __shfl_xor(mx, off));
        float ex = valid ? __expf(e - mx) : 0.f;
        float sum = ex;
#pragma unroll
        for (int off = 16; off; off >>= 1) sum += __shfl_xor(sum, off);
        sa[wave][hf][fl32] = make_int2(s_reg, __float_as_int(ex / sum));

#pragma unroll 2
        for (int eb = 0; eb < deg; eb += 4) {
            int e0 = eb + g;
            int2 q = sa[wave][hf][(e0 < 32) ? e0 : 31];
            float a = (e0 < deg) ? af(q.y) : 0.f;
            const uint2* hr = (const uint2*)(h2b + (size_t)q.x * 16);
            uint2 u = hr[fl];
            acc[0] = fmaf(a, bf_lo(u.x), acc[0]);   // feat 2fl
            acc[1] = fmaf(a, bf_hi(u.x), acc[1]);   // feat 2fl+16
            acc[2] = fmaf(a, bf_lo(u.y), acc[2]);   // feat 2fl+1
            acc[3] = fmaf(a, bf_hi(u.y), acc[3]);   // feat 2fl+17
        }
    } else {
        float mx = -1e30f;
        for (int p = start + fl32; p < start + deg; p += 32)
            mx = fmaxf(mx, lrelu(asrc[esrc[p]] + ad));
#pragma unroll
        for (int off = 16; off; off >>= 1) mx = fmaxf(mx, __shfl_xor(mx, off));
        float sum = 0.f;
        for (int p = start + fl32; p < start + deg; p += 32)
            sum += __expf(lrelu(asrc[esrc[p]] + ad) - mx);
#pragma unroll
        for (int off = 16; off; off >>= 1) sum += __shfl_xor(sum, off);
        float inv = 1.f / sum;
        for (int p = start + g; p < start + deg; p += 4) {
            int s = esrc[p];                          // 8 lanes same addr: broadcast
            float a = __expf(lrelu(asrc[s] + ad) - mx) * inv;
            const uint2* hr = (const uint2*)(h2b + (size_t)s * 16);
            uint2 u = hr[fl];
            acc[0] = fmaf(a, bf_lo(u.x), acc[0]);
            acc[1] = fmaf(a, bf_hi(u.x), acc[1]);
            acc[2] = fmaf(a, bf_lo(u.y), acc[2]);
            acc[3] = fmaf(a, bf_hi(u.y), acc[3]);
        }
    }

    // reduce over the 4 groups within the half
#pragma unroll
    for (int j = 0; j < 4; ++j) {
        acc[j] += __shfl_xor(acc[j], 8);
        acc[j] += __shfl_xor(acc[j], 16);
    }

    // log_softmax over 32 classes spread across lanes fl (8) x 4 values
    float z0 = acc[0] + bias[2 * fl];
    float z1 = acc[1] + bias[2 * fl + 16];
    float z2 = acc[2] + bias[2 * fl + 1];
    float z3 = acc[3] + bias[2 * fl + 17];
    float m2 = fmaxf(fmaxf(z0, z1), fmaxf(z2, z3));
#pragma unroll
    for (int off = 4; off; off >>= 1) m2 = fmaxf(m2, __shfl_xor(m2, off));
    float s2 = __expf(z0 - m2) + __expf(z1 - m2) + __expf(z2 - m2) + __expf(z3 - m2);
#pragma unroll
    for (int off = 4; off; off >>= 1) s2 += __shfl_xor(s2, off);
    float ls = m2 + __logf(s2);
    if (fl32 < 8) {
        float* op = out + (size_t)i * 32;
        op[2 * fl]      = z0 - ls;
        op[2 * fl + 16] = z1 - ls;
        op[2 * fl + 1]  = z2 - ls;
        op[2 * fl + 17] = z3 - ls;
    }
}

// ---------------- launch ----------------

extern "C" void kernel_launch(void* const* d_in, const int* in_sizes, int n_in,
                              void* d_out, int out_size, void* d_ws, size_t ws_size,
                              hipStream_t stream) {
    const float* x   = (const float*)d_in[0];
    const int*   ei  = (const int*)d_in[1];
    const float* W1  = (const float*)d_in[2];
    const float* a1s = (const float*)d_in[3];
    const float* a1d = (const float*)d_in[4];
    const float* b1  = (const float*)d_in[5];
    const float* W2  = (const float*)d_in[6];
    const float* a2s = (const float*)d_in[7];
    const float* a2d = (const float*)d_in[8];
    const float* b2  = (const float*)d_in[9];
    float* out = (float*)d_out;

    size_t off = 0;
    auto alloc = [&](size_t bytes) {
        void* p = (char*)d_ws + off;
        off += (bytes + 255) & ~(size_t)255;
        return p;
    };
    ushort* h1    = (ushort*)alloc((size_t)NNODES * HID * 2);   // bf16, 9.6 MB
    uint32* h2b   = (uint32*)alloc((size_t)NNODES * 16 * 4);    // bf16x2, 3.2 MB
    int*  staging = (int*)alloc((size_t)NBUCK * BCAP * 4);      // 4.8 MB
    float* as1    = (float*)alloc((size_t)NNODES * 4);
    float* ad1    = (float*)alloc((size_t)NNODES * 4);
    float* as2    = (float*)alloc((size_t)NNODES * 4);
    float* ad2    = (float*)alloc((size_t)NNODES * 4);
    int*   rowptr = (int*)alloc((size_t)(NNODES + 1) * 4);
    int*   esrc   = (int*)alloc((size_t)MEDGES * 4);
    ushort* W1p   = (ushort*)alloc((size_t)6 * 8 * 64 * 8 * 2); // 48 KiB
    int*   gcount = (int*)alloc((size_t)NBUCK * 4);

    const int nbB1    = (MEDGES + 2047) / 2048;  // 416
    const int nbGemm  = (NNODES + 63) / 64;      // 782
    const int nbAggP  = NNODES / 8;              // 6250 (exact)

    packw_kernel<<<16, 256, 0, stream>>>(W1, W1p, gcount);
    bucket1_kernel<<<nbB1, 256, 0, stream>>>(ei, gcount, staging);
    // bucket2 (needs bucket1) overlapped with gemm1 (needs packw): independent
    b2gemm1_kernel<<<NBUCK + nbGemm, 256, 0, stream>>>(staging, gcount, rowptr, esrc,
                                                       x, W1p, a1s, a1d, h1, as1, ad1);
    // layer-1 agg + fused layer-2 GEMM (out1b round-trip eliminated)
    agg96g2_kernel<<<nbAggP, 256, 0, stream>>>(h1, as1, ad1, b1, rowptr, esrc,
                                               W2, a2s, a2d, h2b, as2, ad2);
    agg32_kernel<<<nbAggP, 256, 0, stream>>>(h2b, as2, ad2, b2, rowptr, esrc, out);
}

// Round 4
// 210.774 us; speedup vs baseline: 1.0214x; 1.0214x over previous
//
#include <hip/hip_runtime.h>
#include <cstdint>
#include <cstddef>

#define NNODES 50000
#define NEDGES 800000
#define MEDGES (NEDGES + NNODES)
#define FIN    256
#define HID    96
#define NCLS   32
#define NEG_SLOPE 0.2f

#define NBUCK  391      // ceil(50000/128): 128-node dst ranges
#define BCAP   3072     // per-bucket staging capacity (mean 2176, sigma ~45)

typedef unsigned int uint32;
typedef __attribute__((ext_vector_type(8))) short short8;   // 8 bf16 = 4 VGPR
typedef __attribute__((ext_vector_type(4))) float f32x4;    // MFMA acc

__device__ __forceinline__ ushort bf_round(float f) {
    uint32 u = __float_as_uint(f);
    u += 0x7FFFu + ((u >> 16) & 1u);            // RNE
    return (ushort)(u >> 16);
}
__device__ __forceinline__ uint32 pack_bf16x2(float a, float b) {
    return (uint32)bf_round(a) | ((uint32)bf_round(b) << 16);
}
__device__ __forceinline__ float bf_lo(uint32 u) { return __uint_as_float(u << 16); }
__device__ __forceinline__ float bf_hi(uint32 u) { return __uint_as_float(u & 0xFFFF0000u); }
__device__ __forceinline__ float lrelu(float t) { return (t > 0.f) ? t : NEG_SLOPE * t; }
__device__ __forceinline__ float af(int i) { return __int_as_float(i); }
__device__ __forceinline__ float elu_fast(float t) { return (t > 0.f) ? t : (__expf(t) - 1.f); }

// ---------------- W1-pack + gcount zero (must precede bucket1's atomics) ----------------

__global__ __launch_bounds__(256) void packw_kernel(const float* __restrict__ W1,
                                                    ushort* __restrict__ W1p,
                                                    int* __restrict__ gcount) {
    int stride = gridDim.x * 256;
    for (int idx = blockIdx.x * 256 + threadIdx.x; idx < NBUCK; idx += stride)
        gcount[idx] = 0;
    for (int idx = blockIdx.x * 256 + threadIdx.x; idx < 6 * 8 * 64 * 8; idx += stride) {
        int j     = idx & 7;
        int lane  = (idx >> 3) & 63;
        int kstep = (idx >> 9) & 7;
        int ntile = idx >> 12;
        int k = kstep * 32 + ((lane >> 4) << 3) + j;
        int n = ntile * 16 + (lane & 15);
        W1p[idx] = bf_round(W1[(size_t)k * 96 + n]);
    }
}

// ---------------- CSR build pass 1: bucketed staging ----------------
// staging entry packed: src (16 bits, 50000<65536) | (dst&127)<<16.

__global__ __launch_bounds__(256) void bucket1_kernel(const int* __restrict__ ei,
                                                      int* __restrict__ gcount,
                                                      int* __restrict__ staging) {
    __shared__ int hist[NBUCK];
    __shared__ int base_sh[NBUCK];
    for (int i = threadIdx.x; i < NBUCK; i += 256) hist[i] = 0;
    __syncthreads();

    int v[8], rk[8], bk[8];
    int e0 = blockIdx.x * 2048;
#pragma unroll
    for (int i = 0; i < 8; ++i) {
        int e = e0 + i * 256 + threadIdx.x;
        if (e < MEDGES) {
            int s, d;
            if (e < NEDGES) { s = ei[e]; d = ei[NEDGES + e]; }
            else            { s = e - NEDGES; d = s; }
            bk[i] = d >> 7;
            v[i]  = s | ((d & 127) << 16);
            rk[i] = atomicAdd(&hist[bk[i]], 1);
        } else bk[i] = -1;
    }
    __syncthreads();
    for (int i = threadIdx.x; i < NBUCK; i += 256) {
        int c = hist[i];
        base_sh[i] = c ? atomicAdd(&gcount[i], c) : 0;
    }
    __syncthreads();
#pragma unroll
    for (int i = 0; i < 8; ++i) {
        if (bk[i] >= 0) {
            int pos = base_sh[bk[i]] + rk[i];
            if (pos < BCAP)
                staging[(size_t)bk[i] * BCAP + pos] = v[i];
        }
    }
}

// ---------------- merged dispatch: bucket2 (blocks 0..390) + gemm1 (391..1172) ----------------

__global__ __launch_bounds__(256) void b2gemm1_kernel(const int* __restrict__ staging,
                                                      const int* __restrict__ gcount,
                                                      int* __restrict__ rowptr,
                                                      int* __restrict__ esrc,
                                                      const float* __restrict__ x,
                                                      const ushort* __restrict__ W1p,
                                                      const float* __restrict__ a_src,
                                                      const float* __restrict__ a_dst,
                                                      ushort* __restrict__ h1,
                                                      float* __restrict__ as1,
                                                      float* __restrict__ ad1) {
    __shared__ int dcount[128];
    __shared__ int dincl[128];
    __shared__ int dexcl[128];
    __shared__ int fillc[128];
    __shared__ int red_s[256];

    if (blockIdx.x < NBUCK) {
        // ---- bucket2: rowptr + esrc build for bucket b ----
        const int b = blockIdx.x;
        const int t = threadIdx.x;

        int pv = 0;
        for (int idx = t; idx < b; idx += 256) pv += gcount[idx];
        red_s[t] = pv;
        __syncthreads();
        for (int off2 = 128; off2; off2 >>= 1) {
            if (t < off2) red_s[t] += red_s[t + off2];
            __syncthreads();
        }
        const int ebase = red_s[0];
        const int cnt   = gcount[b];
        const int node0 = b << 7;
        const int* st   = staging + (size_t)b * BCAP;

        for (int i = t; i < 128; i += 256) { dcount[i] = 0; fillc[i] = 0; }
        __syncthreads();

        for (int i = t; i < cnt; i += 256)
            atomicAdd(&dcount[st[i] >> 16], 1);
        __syncthreads();

        if (t < 128) dincl[t] = dcount[t];
        __syncthreads();
        for (int off = 1; off < 128; off <<= 1) {
            int val = (t >= off && t < 128) ? dincl[t - off] : 0;
            __syncthreads();
            if (t < 128) dincl[t] += val;
            __syncthreads();
        }
        if (t < 128) {
            int excl = dincl[t] - dcount[t];
            dexcl[t] = excl;
            int node = node0 + t;
            if (node < NNODES) rowptr[node] = ebase + excl;
        }
        if (b == NBUCK - 1 && t == 0) rowptr[NNODES] = MEDGES;
        __syncthreads();

        for (int i = t; i < cnt; i += 256) {
            int v = st[i];
            int dd = v >> 16;
            int r = atomicAdd(&fillc[dd], 1);
            esrc[ebase + dexcl[dd] + r] = v & 0xFFFF;
        }
        return;
    }

    // ---- gemm1: h1(bf16) = x @ W1 (+ fused alpha dots) ----
    const int tid  = threadIdx.x;
    const int lane = tid & 63;
    const int wv   = tid >> 6;
    const int m    = lane & 15;
    const int quad = lane >> 4;
    const int node0 = (blockIdx.x - NBUCK) * 64;

    int arow = node0 + wv * 16 + m;
    if (arow >= NNODES) arow = NNODES - 1;
    const float* xr = x + (size_t)arow * FIN + quad * 8;

    const short8* Wp = (const short8*)W1p;

    f32x4 acc[6];
#pragma unroll
    for (int t = 0; t < 6; ++t) acc[t] = (f32x4){0.f, 0.f, 0.f, 0.f};

#pragma unroll
    for (int ks = 0; ks < 8; ++ks) {
        float4 v0 = *(const float4*)(xr + ks * 32);
        float4 v1 = *(const float4*)(xr + ks * 32 + 4);
        short8 a;
        a[0] = (short)bf_round(v0.x); a[1] = (short)bf_round(v0.y);
        a[2] = (short)bf_round(v0.z); a[3] = (short)bf_round(v0.w);
        a[4] = (short)bf_round(v1.x); a[5] = (short)bf_round(v1.y);
        a[6] = (short)bf_round(v1.z); a[7] = (short)bf_round(v1.w);
#pragma unroll
        for (int t = 0; t < 6; ++t) {
            short8 b = Wp[(t * 8 + ks) * 64 + lane];
            acc[t] = __builtin_amdgcn_mfma_f32_16x16x32_bf16(a, b, acc[t], 0, 0, 0);
        }
    }

    float as_reg[6], ad_reg[6];
#pragma unroll
    for (int t = 0; t < 6; ++t) {
        as_reg[t] = a_src[t * 16 + m];
        ad_reg[t] = a_dst[t * 16 + m];
    }

#pragma unroll
    for (int r = 0; r < 4; ++r) {
        int node = node0 + wv * 16 + quad * 4 + r;
        float ps = 0.f, pd = 0.f;
#pragma unroll
        for (int t = 0; t < 6; ++t) {
            ps += acc[t][r] * as_reg[t];
            pd += acc[t][r] * ad_reg[t];
        }
#pragma unroll
        for (int off = 1; off < 16; off <<= 1) {
            ps += __shfl_xor(ps, off);
            pd += __shfl_xor(pd, off);
        }
        if (node < NNODES) {
            ushort* hp = h1 + (size_t)node * 96 + m;
#pragma unroll
            for (int t = 0; t < 6; ++t) hp[t * 16] = bf_round(acc[t][r]);
            if (m == 0) { as1[node] = ps; ad1[node] = pd; }
        }
    }
}

// ---------------- Fused attn+agg layer 1 + gemm2 epilogue (pipelined, barrier-first) ----------------
// Round-3 lesson: __syncthreads between gather-issue and consume drains
// vmcnt(0) -> prefetch useless. Fix: stage W2 + barrier at the VERY TOP
// (nothing in flight yet), then issue the 16 h-row gathers right after the
// src indices land, and run the whole softmax chain under them. No barrier
// between issue and consume; only the compiler's counted vmcnt waits.

#define LOADB(U, qa, qb) do { \
    U[0] = ((const uint2*)(h + (size_t)(qa).x * 96))[fl]; \
    U[1] = ((const uint2*)(h + (size_t)(qa).y * 96))[fl]; \
    U[2] = ((const uint2*)(h + (size_t)(qa).z * 96))[fl]; \
    U[3] = ((const uint2*)(h + (size_t)(qa).w * 96))[fl]; \
    U[4] = ((const uint2*)(h + (size_t)(qb).x * 96))[fl]; \
    U[5] = ((const uint2*)(h + (size_t)(qb).y * 96))[fl]; \
    U[6] = ((const uint2*)(h + (size_t)(qb).z * 96))[fl]; \
    U[7] = ((const uint2*)(h + (size_t)(qb).w * 96))[fl]; \
} while (0)

#define CONSUME(U, aL, aH) do { \
    acc0 += (aL).x*bf_lo(U[0].x) + (aL).y*bf_lo(U[1].x) + (aL).z*bf_lo(U[2].x) + (aL).w*bf_lo(U[3].x) \
          + (aH).x*bf_lo(U[4].x) + (aH).y*bf_lo(U[5].x) + (aH).z*bf_lo(U[6].x) + (aH).w*bf_lo(U[7].x); \
    acc1 += (aL).x*bf_hi(U[0].x) + (aL).y*bf_hi(U[1].x) + (aL).z*bf_hi(U[2].x) + (aL).w*bf_hi(U[3].x) \
          + (aH).x*bf_hi(U[4].x) + (aH).y*bf_hi(U[5].x) + (aH).z*bf_hi(U[6].x) + (aH).w*bf_hi(U[7].x); \
    acc2 += (aL).x*bf_lo(U[0].y) + (aL).y*bf_lo(U[1].y) + (aL).z*bf_lo(U[2].y) + (aL).w*bf_lo(U[3].y) \
          + (aH).x*bf_lo(U[4].y) + (aH).y*bf_lo(U[5].y) + (aH).z*bf_lo(U[6].y) + (aH).w*bf_lo(U[7].y); \
    acc3 += (aL).x*bf_hi(U[0].y) + (aL).y*bf_hi(U[1].y) + (aL).z*bf_hi(U[2].y) + (aL).w*bf_hi(U[3].y) \
          + (aH).x*bf_hi(U[4].y) + (aH).y*bf_hi(U[5].y) + (aH).z*bf_hi(U[6].y) + (aH).w*bf_hi(U[7].y); \
} while (0)

__global__ __launch_bounds__(256) void agg96g2_kernel(const ushort* __restrict__ h,
                                                      const float* __restrict__ asrc,
                                                      const float* __restrict__ adst,
                                                      const float* __restrict__ bias,
                                                      const int* __restrict__ rowptr,
                                                      const int* __restrict__ esrc,
                                                      const float* __restrict__ W2,
                                                      const float* __restrict__ a2s,
                                                      const float* __restrict__ a2d,
                                                      uint32* __restrict__ h2b,
                                                      float* __restrict__ as2,
                                                      float* __restrict__ ad2) {
    __shared__ __align__(16) int   ss[4][2][32];
    __shared__ __align__(16) float aa[4][2][32];
    __shared__ __align__(16) float W2n[96 * 32];      // [k][c] untransposed: lane c -> bank c
    __shared__ __align__(16) float y_sh[4][2][96];

    // ---- stage W2 FIRST: barrier fires with nothing else in flight ----
    for (int idx = threadIdx.x; idx < 96 * 32; idx += 256)
        W2n[idx] = W2[idx];
    __syncthreads();

    const int wave = threadIdx.x >> 6;
    const int lane = threadIdx.x & 63;
    const int hf   = lane >> 5;
    const int fl32 = lane & 31;
    const int i = blockIdx.x * 8 + wave * 2 + hf;   // 50000 = 8*6250 exact

    const int start = rowptr[i];
    const int deg   = rowptr[i + 1] - start;
    const float ad  = adst[i];
    const float a2s_v = a2s[fl32];
    const float a2d_v = a2d[fl32];
    const int fl    = (fl32 < 24) ? fl32 : 23;

    float acc0 = 0.f, acc1 = 0.f, acc2 = 0.f, acc3 = 0.f;

    const bool small = (deg <= 32);

    if (small) {
        // src indices -> 16 gathers in flight BEFORE the softmax chain
        bool valid = fl32 < deg;
        int s_reg = valid ? esrc[start + fl32] : 0;
        ss[wave][hf][fl32] = s_reg;
        int nb = (deg + 7) >> 3;                   // 1..4 blocks of 8 edges
        const int4* ssp = (const int4*)&ss[wave][hf][0];
        uint2 uA[8], uB[8];
        {
            int4 qa = ssp[0], qb = ssp[1];
            LOADB(uA, qa, qb);
        }
        if (nb > 1) {
            int4 qa = ssp[2], qb = ssp[3];
            LOADB(uB, qa, qb);
        }

        // softmax runs while uA/uB gathers are in flight
        float e = valid ? lrelu(asrc[s_reg] + ad) : -1e30f;
        float mx = e;
#pragma unroll
        for (int off = 16; off; off >>= 1) mx = fmaxf(mx, __shfl_xor(mx, off));
        float ex = valid ? __expf(e - mx) : 0.f;
        float sum = ex;
#pragma unroll
        for (int off = 16; off; off >>= 1) sum += __shfl_xor(sum, off);
        aa[wave][hf][fl32] = ex / sum;             // 0 for padded lanes
        const float4* aap = (const float4*)&aa[wave][hf][0];

        { float4 aL = aap[0], aH = aap[1]; CONSUME(uA, aL, aH); }
        if (nb > 2) { int4 qa = ssp[4], qb = ssp[5]; LOADB(uA, qa, qb); }
        if (nb > 1) { float4 aL = aap[2], aH = aap[3]; CONSUME(uB, aL, aH); }
        if (nb > 3) { int4 qa = ssp[6], qb = ssp[7]; LOADB(uB, qa, qb); }
        if (nb > 2) { float4 aL = aap[4], aH = aap[5]; CONSUME(uA, aL, aH); }
        if (nb > 3) { float4 aL = aap[6], aH = aap[7]; CONSUME(uB, aL, aH); }
    } else {
        float mx = -1e30f;
        for (int p = start + fl32; p < start + deg; p += 32)
            mx = fmaxf(mx, lrelu(asrc[esrc[p]] + ad));
#pragma unroll
        for (int off = 16; off; off >>= 1) mx = fmaxf(mx, __shfl_xor(mx, off));
        float sum = 0.f;
        for (int p = start + fl32; p < start + deg; p += 32)
            sum += __expf(lrelu(asrc[esrc[p]] + ad) - mx);
#pragma unroll
        for (int off = 16; off; off >>= 1) sum += __shfl_xor(sum, off);
        float inv = 1.f / sum;
        for (int e = 0; e < deg; ++e) {
            int s = esrc[start + e];
            float a = __expf(lrelu(asrc[s] + ad) - mx) * inv;
            uint2 u = ((const uint2*)(h + (size_t)s * 96))[fl];
            acc0 += a * bf_lo(u.x);
            acc1 += a * bf_hi(u.x);
            acc2 += a * bf_lo(u.y);
            acc3 += a * bf_hi(u.y);
        }
    }

    // ---- epilogue: bias + ELU -> y_sh, then fused h2 = y @ W2 ----
    if (fl32 < 24) {
        float* yp = &y_sh[wave][hf][4 * fl32];
        yp[0] = elu_fast(acc0 + bias[4 * fl32 + 0]);
        yp[1] = elu_fast(acc1 + bias[4 * fl32 + 1]);
        yp[2] = elu_fast(acc2 + bias[4 * fl32 + 2]);
        yp[3] = elu_fast(acc3 + bias[4 * fl32 + 3]);
    }
    asm volatile("s_waitcnt lgkmcnt(0)" ::: "memory");   // wave-internal y_sh visibility

    const float* yrow = &y_sh[wave][hf][0];
    float h2c = 0.f;
#pragma unroll
    for (int k4 = 0; k4 < 96; k4 += 4) {
        float4 yv = *(const float4*)(yrow + k4);       // broadcast within half
        h2c = fmaf(yv.x, W2n[(k4 + 0) * 32 + fl32], h2c);   // lane c -> bank c
        h2c = fmaf(yv.y, W2n[(k4 + 1) * 32 + fl32], h2c);
        h2c = fmaf(yv.z, W2n[(k4 + 2) * 32 + fl32], h2c);
        h2c = fmaf(yv.w, W2n[(k4 + 3) * 32 + fl32], h2c);
    }

    float ps = h2c * a2s_v;
    float pd = h2c * a2d_v;
#pragma unroll
    for (int off = 1; off < 32; off <<= 1) {        // reduce within 32-lane half
        ps += __shfl_xor(ps, off);
        pd += __shfl_xor(pd, off);
    }
    float partner = __shfl_xor(h2c, 16);            // class c+16 for c<16
    if (fl32 < 16)
        h2b[(size_t)i * 16 + fl32] = pack_bf16x2(h2c, partner);
    if (fl32 == 0) { as2[i] = ps; ad2[i] = pd; }
}

// ---------------- Fused attn + aggregation layer 2: TWO nodes per wave ----------------
// Half-wave per node; 4 groups x 8 lanes read 64 B h2b rows via dwordx2
// -> 8 edges per wave-VMEM-instruction across 2 independent streams.
// h2b uint32 index m holds feats (m, m+16).

__global__ __launch_bounds__(256) void agg32_kernel(const uint32* __restrict__ h2b,
                                                    const float* __restrict__ asrc,
                                                    const float* __restrict__ adst,
                                                    const float* __restrict__ bias,
                                                    const int* __restrict__ rowptr,
                                                    const int* __restrict__ esrc,
                                                    float* __restrict__ out) {
    __shared__ int2 sa[4][2][32];
    const int wave = threadIdx.x >> 6;
    const int lane = threadIdx.x & 63;
    const int hf   = lane >> 5;
    const int fl32 = lane & 31;
    const int i = blockIdx.x * 8 + wave * 2 + hf;   // 6250 blocks exact

    const int start = rowptr[i];
    const int deg   = rowptr[i + 1] - start;
    const float ad  = adst[i];
    const int g  = fl32 >> 3;        // edge group 0..3 within half
    const int fl = fl32 & 7;         // uint2 index within row

    float acc[4];
#pragma unroll
    for (int j = 0; j < 4; ++j) acc[j] = 0.f;

    if (deg <= 32) {
        bool valid = fl32 < deg;
        int s_reg = valid ? esrc[start + fl32] : 0;
        float e = valid ? lrelu(asrc[s_reg] + ad) : -1e30f;
        float mx = e;
#pragma unroll
        for (int off = 16; off; off >>= 1) mx = fmaxf(mx, __shfl_xor(mx, off));
        float ex = valid ? __expf(e - mx) : 0.f;
        float sum = ex;
#pragma unroll
        for (int off = 16; off; off >>= 1) sum += __shfl_xor(sum, off);
        sa[wave][hf][fl32] = make_int2(s_reg, __float_as_int(ex / sum));

#pragma unroll 2
        for (int eb = 0; eb < deg; eb += 4) {
            int e0 = eb + g;
            int2 q = sa[wave][hf][(e0 < 32) ? e0 : 31];
            float a = (e0 < deg) ? af(q.y) : 0.f;
            const uint2* hr = (const uint2*)(h2b + (size_t)q.x * 16);
            uint2 u = hr[fl];
            acc[0] = fmaf(a, bf_lo(u.x), acc[0]);   // feat 2fl
            acc[1] = fmaf(a, bf_hi(u.x), acc[1]);   // feat 2fl+16
            acc[2] = fmaf(a, bf_lo(u.y), acc[2]);   // feat 2fl+1
            acc[3] = fmaf(a, bf_hi(u.y), acc[3]);   // feat 2fl+17
        }
    } else {
        float mx = -1e30f;
        for (int p = start + fl32; p < start + deg; p += 32)
            mx = fmaxf(mx, lrelu(asrc[esrc[p]] + ad));
#pragma unroll
        for (int off = 16; off; off >>= 1) mx = fmaxf(mx, __shfl_xor(mx, off));
        float sum = 0.f;
        for (int p = start + fl32; p < start + deg; p += 32)
            sum += __expf(lrelu(asrc[esrc[p]] + ad) - mx);
#pragma unroll
        for (int off = 16; off; off >>= 1) sum += __shfl_xor(sum, off);
        float inv = 1.f / sum;
        for (int p = start + g; p < start + deg; p += 4) {
            int s = esrc[p];                          // 8 lanes same addr: broadcast
            float a = __expf(lrelu(asrc[s] + ad) - mx) * inv;
            const uint2* hr = (const uint2*)(h2b + (size_t)s * 16);
            uint2 u = hr[fl];
            acc[0] = fmaf(a, bf_lo(u.x), acc[0]);
            acc[1] = fmaf(a, bf_hi(u.x), acc[1]);
            acc[2] = fmaf(a, bf_lo(u.y), acc[2]);
            acc[3] = fmaf(a, bf_hi(u.y), acc[3]);
        }
    }

    // reduce over the 4 groups within the half
#pragma unroll
    for (int j = 0; j < 4; ++j) {
        acc[j] += __shfl_xor(acc[j], 8);
        acc[j] += __shfl_xor(acc[j], 16);
    }

    // log_softmax over 32 classes spread across lanes fl (8) x 4 values
    float z0 = acc[0] + bias[2 * fl];
    float z1 = acc[1] + bias[2 * fl + 16];
    float z2 = acc[2] + bias[2 * fl + 1];
    float z3 = acc[3] + bias[2 * fl + 17];
    float m2 = fmaxf(fmaxf(z0, z1), fmaxf(z2, z3));
#pragma unroll
    for (int off = 4; off; off >>= 1) m2 = fmaxf(m2, __shfl_xor(m2, off));
    float s2 = __expf(z0 - m2) + __expf(z1 - m2) + __expf(z2 - m2) + __expf(z3 - m2);
#pragma unroll
    for (int off = 4; off; off >>= 1) s2 += __shfl_xor(s2, off);
    float ls = m2 + __logf(s2);
    if (fl32 < 8) {
        float* op = out + (size_t)i * 32;
        op[2 * fl]      = z0 - ls;
        op[2 * fl + 16] = z1 - ls;
        op[2 * fl + 1]  = z2 - ls;
        op[2 * fl + 17] = z3 - ls;
    }
}

// ---------------- launch ----------------

extern "C" void kernel_launch(void* const* d_in, const int* in_sizes, int n_in,
                              void* d_out, int out_size, void* d_ws, size_t ws_size,
                              hipStream_t stream) {
    const float* x   = (const float*)d_in[0];
    const int*   ei  = (const int*)d_in[1];
    const float* W1  = (const float*)d_in[2];
    const float* a1s = (const float*)d_in[3];
    const float* a1d = (const float*)d_in[4];
    const float* b1  = (const float*)d_in[5];
    const float* W2  = (const float*)d_in[6];
    const float* a2s = (const float*)d_in[7];
    const float* a2d = (const float*)d_in[8];
    const float* b2  = (const float*)d_in[9];
    float* out = (float*)d_out;

    size_t off = 0;
    auto alloc = [&](size_t bytes) {
        void* p = (char*)d_ws + off;
        off += (bytes + 255) & ~(size_t)255;
        return p;
    };
    ushort* h1    = (ushort*)alloc((size_t)NNODES * HID * 2);   // bf16, 9.6 MB
    uint32* h2b   = (uint32*)alloc((size_t)NNODES * 16 * 4);    // bf16x2, 3.2 MB
    int*  staging = (int*)alloc((size_t)NBUCK * BCAP * 4);      // 4.8 MB
    float* as1    = (float*)alloc((size_t)NNODES * 4);
    float* ad1    = (float*)alloc((size_t)NNODES * 4);
    float* as2    = (float*)alloc((size_t)NNODES * 4);
    float* ad2    = (float*)alloc((size_t)NNODES * 4);
    int*   rowptr = (int*)alloc((size_t)(NNODES + 1) * 4);
    int*   esrc   = (int*)alloc((size_t)MEDGES * 4);
    ushort* W1p   = (ushort*)alloc((size_t)6 * 8 * 64 * 8 * 2); // 48 KiB
    int*   gcount = (int*)alloc((size_t)NBUCK * 4);

    const int nbB1    = (MEDGES + 2047) / 2048;  // 416
    const int nbGemm  = (NNODES + 63) / 64;      // 782
    const int nbAggP  = NNODES / 8;              // 6250 (exact)

    packw_kernel<<<16, 256, 0, stream>>>(W1, W1p, gcount);
    bucket1_kernel<<<nbB1, 256, 0, stream>>>(ei, gcount, staging);
    // bucket2 (needs bucket1) overlapped with gemm1 (needs packw): independent
    b2gemm1_kernel<<<NBUCK + nbGemm, 256, 0, stream>>>(staging, gcount, rowptr, esrc,
                                                       x, W1p, a1s, a1d, h1, as1, ad1);
    // layer-1 agg + fused layer-2 GEMM (out1b round-trip eliminated)
    agg96g2_kernel<<<nbAggP, 256, 0, stream>>>(h1, as1, ad1, b1, rowptr, esrc,
                                               W2, a2s, a2d, h2b, as2, ad2);
    agg32_kernel<<<nbAggP, 256, 0, stream>>>(h2b, as2, ad2, b2, rowptr, esrc, out);
}